// Round 3
// baseline (589.557 us; speedup 1.0000x reference)
//
#include <hip/hip_runtime.h>
#include <hip/hip_bf16.h>
#include <stdint.h>

#define Bb 16
#define Ss 1024
#define Dd 1024
#define NHh 16
#define HDd 64
#define Mm 16384  // Bb*Ss

typedef _Float16 half8 __attribute__((ext_vector_type(8)));
typedef float f32x4 __attribute__((ext_vector_type(4)));

__device__ __forceinline__ void gload_lds16(const _Float16* g, _Float16* l) {
  auto* gp = (const __attribute__((address_space(1))) unsigned int*)(g);
  auto* lp = (__attribute__((address_space(3))) unsigned int*)(l);
  __builtin_amdgcn_global_load_lds(gp, lp, 16, 0, 0);
}

// ---------------- cast fp32 -> fp16 (x and concatenated weights) ----------------
__global__ void cast_all(const float* __restrict__ x,
                         const float* __restrict__ wq, const float* __restrict__ wk,
                         const float* __restrict__ wv, const float* __restrict__ wo,
                         _Float16* __restrict__ xh, _Float16* __restrict__ wcat) {
  const long NX = (long)Mm * Dd / 4;   // 4194304 chunks of 4 floats
  const long NW = (long)Dd * Dd / 4;   // 262144 per weight matrix
  long c = (long)blockIdx.x * blockDim.x + threadIdx.x;
  const float* src;
  _Float16* dst;
  long o;
  if (c < NX) {
    src = x; o = c; dst = xh;
  } else {
    long cw = c - NX;
    int m = (int)(cw / NW);
    o = cw - (long)m * NW;
    src = (m == 0) ? wq : (m == 1) ? wk : (m == 2) ? wv : wo;
    dst = wcat + (long)m * (Dd * Dd);
  }
  float4 v = reinterpret_cast<const float4*>(src)[o];
  _Float16 h[4] = {(_Float16)v.x, (_Float16)v.y, (_Float16)v.z, (_Float16)v.w};
  reinterpret_cast<uint64_t*>(dst)[o] = *reinterpret_cast<uint64_t*>(h);
}

// ---------------- NT GEMM: C[m,n] = sum_k A[m,k]*B[n,k], 128x128x32 tiles ----------------
// EPI 0: QKV projection epilogue (bias + RoPE + scatter to (b,h,s,d) fp16)
// EPI 1: out projection epilogue (bias + fp32 store)
template <int EPI>
__global__ __launch_bounds__(256, 2) void gemm_nt(
    const _Float16* __restrict__ A, const _Float16* __restrict__ Bm,
    _Float16* __restrict__ qo, _Float16* __restrict__ ko, _Float16* __restrict__ vo,
    const float* __restrict__ bq, const float* __restrict__ bk, const float* __restrict__ bv,
    const float* __restrict__ cosp, const float* __restrict__ sinp,
    float* __restrict__ outp, const float* __restrict__ bo) {
  __shared__ __align__(16) _Float16 As[128 * 32];
  __shared__ __align__(16) _Float16 Bs[128 * 32];
  const int t = threadIdx.x;
  const int w = t >> 6, l = t & 63;
  const int g = l >> 4, ln = l & 15;
  const int wr = w >> 1, wc = w & 1;
  const long rowbase = (long)blockIdx.y * 128;
  const long colbase = (long)blockIdx.x * 128;
  const _Float16* Arow0 = A + rowbase * Dd;
  const _Float16* Brow0 = Bm + colbase * Dd;

  f32x4 acc[4][4];
#pragma unroll
  for (int i = 0; i < 4; ++i)
#pragma unroll
    for (int j = 0; j < 4; ++j) acc[i][j] = f32x4{0.f, 0.f, 0.f, 0.f};

  for (int kt = 0; kt < 32; ++kt) {
    const int kof = kt * 32;
#pragma unroll
    for (int h = 0; h < 2; ++h) {
      int chunk = t + h * 256;          // 0..511 ; 16B per chunk
      int r = chunk >> 2;
      int cc = (chunk & 3) * 8;
      gload_lds16(Arow0 + (long)r * Dd + kof + cc, &As[chunk * 8]);
      gload_lds16(Brow0 + (long)r * Dd + kof + cc, &Bs[chunk * 8]);
    }
    __syncthreads();
    half8 af[4], bf[4];
#pragma unroll
    for (int i = 0; i < 4; ++i) {
      af[i] = *reinterpret_cast<const half8*>(&As[(wr * 64 + i * 16 + ln) * 32 + g * 8]);
      bf[i] = *reinterpret_cast<const half8*>(&Bs[(wc * 64 + i * 16 + ln) * 32 + g * 8]);
    }
#pragma unroll
    for (int i = 0; i < 4; ++i)
#pragma unroll
      for (int j = 0; j < 4; ++j)
        acc[i][j] = __builtin_amdgcn_mfma_f32_16x16x32_f16(af[i], bf[j], acc[i][j], 0, 0, 0);
    __syncthreads();
  }

  if (EPI == 0) {
#pragma unroll
    for (int j = 0; j < 4; ++j) {
      long n = colbase + wc * 64 + j * 16 + ln;
      int mat = (int)(n >> 10);          // 0=q 1=k 2=v (uniform across wave)
      int col = (int)(n & 1023);
      int hh = col >> 6, hd = col & 63;
      float bias = (mat == 0) ? bq[col] : (mat == 1) ? bk[col] : bv[col];
      _Float16* dst = (mat == 0) ? qo : (mat == 1) ? ko : vo;
#pragma unroll
      for (int i = 0; i < 4; ++i) {
#pragma unroll
        for (int r = 0; r < 4; ++r) {
          long row = rowbase + wr * 64 + i * 16 + g * 4 + r;
          int b = (int)(row >> 10), s = (int)(row & 1023);
          float val = acc[i][j][r] + bias;
          if (mat < 2) {
            float part = __shfl_xor(val, 1);
            float cv = cosp[s * HDd + hd];
            float sv = sinp[s * HDd + hd];
            val = val * cv + ((hd & 1) ? part : -part) * sv;
          }
          dst[((long)(b * NHh + hh) * Ss + s) * HDd + hd] = (_Float16)val;
        }
      }
    }
  } else {
#pragma unroll
    for (int j = 0; j < 4; ++j) {
      long n = colbase + wc * 64 + j * 16 + ln;
      float bias = bo[n];
#pragma unroll
      for (int i = 0; i < 4; ++i)
#pragma unroll
        for (int r = 0; r < 4; ++r) {
          long row = rowbase + wr * 64 + i * 16 + g * 4 + r;
          outp[row * Dd + n] = acc[i][j][r] + bias;
        }
    }
  }
}

// ---------------- flash attention: one block = 64 q-rows of one (b,h) pair ----------------
__global__ __launch_bounds__(256, 2) void attn(
    const _Float16* __restrict__ Q, const _Float16* __restrict__ K,
    const _Float16* __restrict__ V, _Float16* __restrict__ O) {
  __shared__ __align__(16) _Float16 Ks[64 * 72];   // [krow][d] padded
  __shared__ __align__(16) _Float16 Vt[64 * 72];   // [d][krow] padded
  __shared__ __align__(16) _Float16 Ps[4 * 16 * 72];  // per-wave [q][kcol] padded
  const int t = threadIdx.x;
  const int w = t >> 6, l = t & 63;
  const int g = l >> 4, ln = l & 15;
  const int pair = blockIdx.y;       // b*16 + h
  const int qbase = blockIdx.x * 64;
  const long pbase = (long)pair * Ss * HDd;
  const float scale = 0.125f;        // 64^-0.5

  // Q fragments for this wave's 16 q-rows (held in registers for all iterations)
  half8 qf[2];
  {
    long qr = qbase + w * 16 + ln;
    const _Float16* qp = Q + pbase + qr * HDd + g * 8;
    qf[0] = *reinterpret_cast<const half8*>(qp);
    qf[1] = *reinterpret_cast<const half8*>(qp + 32);
  }

  float m_i = -1e30f, l_i = 0.0f;
  f32x4 acc_o[4];
#pragma unroll
  for (int c = 0; c < 4; ++c) acc_o[c] = f32x4{0.f, 0.f, 0.f, 0.f};

  for (int kt = 0; kt < 16; ++kt) {
    // stage K tile [64][64] and transposed V tile: 4096 halfs each ->
    // 256 threads x 2 chunks x 8 halfs (FULL coverage; round-1 bug was half)
#pragma unroll
    for (int h2 = 0; h2 < 2; ++h2) {
      int chunk = t + h2 * 256;        // 0..511
      int r = chunk >> 3;              // 0..63
      int cc = (chunk & 7) * 8;        // 0..56
      const _Float16* kp = K + pbase + (long)(kt * 64 + r) * HDd + cc;
      half8 kv = *reinterpret_cast<const half8*>(kp);
      *reinterpret_cast<half8*>(&Ks[r * 72 + cc]) = kv;
      const _Float16* vp = V + pbase + (long)(kt * 64 + r) * HDd + cc;
      half8 vv = *reinterpret_cast<const half8*>(vp);
#pragma unroll
      for (int jj = 0; jj < 8; ++jj) Vt[(cc + jj) * 72 + r] = vv[jj];
    }
    __syncthreads();

    // S^T tile: mfma(A=K rows, B=Q^T) -> D[kcol][qrow]
    f32x4 accs[4];
#pragma unroll
    for (int c = 0; c < 4; ++c) {
      half8 kf0 = *reinterpret_cast<const half8*>(&Ks[(c * 16 + ln) * 72 + g * 8]);
      half8 kf1 = *reinterpret_cast<const half8*>(&Ks[(c * 16 + ln) * 72 + 32 + g * 8]);
      f32x4 a = f32x4{0.f, 0.f, 0.f, 0.f};
      a = __builtin_amdgcn_mfma_f32_16x16x32_f16(kf0, qf[0], a, 0, 0, 0);
      a = __builtin_amdgcn_mfma_f32_16x16x32_f16(kf1, qf[1], a, 0, 0, 0);
      accs[c] = a;
    }

    // online softmax for row q = ln (redundant across the 4 lane-groups)
    float pv[16];
    float pmax = -1e30f;
#pragma unroll
    for (int c = 0; c < 4; ++c)
#pragma unroll
      for (int r = 0; r < 4; ++r) {
        float sv = accs[c][r] * scale;
        pv[c * 4 + r] = sv;
        pmax = fmaxf(pmax, sv);
      }
    pmax = fmaxf(pmax, __shfl_xor(pmax, 16));
    pmax = fmaxf(pmax, __shfl_xor(pmax, 32));
    float m_new = fmaxf(m_i, pmax);
    float alpha = __expf(m_i - m_new);
    float tsum = 0.0f;
#pragma unroll
    for (int z = 0; z < 16; ++z) {
      float e = __expf(pv[z] - m_new);
      pv[z] = e;
      tsum += e;
    }
    tsum += __shfl_xor(tsum, 16);
    tsum += __shfl_xor(tsum, 32);
    l_i = l_i * alpha + tsum;
    m_i = m_new;

    // rescale acc_o rows (q = 4g + r) by that row's alpha
    float alr[4];
#pragma unroll
    for (int r = 0; r < 4; ++r) alr[r] = __shfl(alpha, g * 4 + r);
#pragma unroll
    for (int c = 0; c < 4; ++c)
#pragma unroll
      for (int r = 0; r < 4; ++r) acc_o[c][r] *= alr[r];

    // write P (fp16) to per-wave LDS: row q=ln, cols c*16+4g+r
    _Float16* prow = &Ps[(w * 16 + ln) * 72];
#pragma unroll
    for (int c = 0; c < 4; ++c) {
      _Float16 p4[4] = {(_Float16)pv[c * 4 + 0], (_Float16)pv[c * 4 + 1],
                        (_Float16)pv[c * 4 + 2], (_Float16)pv[c * 4 + 3]};
      *reinterpret_cast<uint2*>(&prow[c * 16 + g * 4]) = *reinterpret_cast<uint2*>(p4);
    }

    // PV: acc_o[c'] += P(16x64) * V(64x16 per sub-tile)
#pragma unroll
    for (int kh = 0; kh < 2; ++kh) {
      half8 pf = *reinterpret_cast<const half8*>(&Ps[(w * 16 + ln) * 72 + kh * 32 + g * 8]);
#pragma unroll
      for (int c = 0; c < 4; ++c) {
        half8 vf = *reinterpret_cast<const half8*>(&Vt[(c * 16 + ln) * 72 + kh * 32 + g * 8]);
        acc_o[c] = __builtin_amdgcn_mfma_f32_16x16x32_f16(pf, vf, acc_o[c], 0, 0, 0);
      }
    }
    __syncthreads();
  }

  // epilogue: normalize rows and store to (b, s, h*64+d) fp16
  const int b = pair >> 4, hh = pair & 15;
  float linv[4];
#pragma unroll
  for (int r = 0; r < 4; ++r) linv[r] = 1.0f / __shfl(l_i, g * 4 + r);
#pragma unroll
  for (int c = 0; c < 4; ++c)
#pragma unroll
    for (int r = 0; r < 4; ++r) {
      int s = qbase + w * 16 + g * 4 + r;
      long addr = ((long)(b * Ss + s)) * Dd + hh * HDd + c * 16 + ln;
      O[addr] = (_Float16)(acc_o[c][r] * linv[r]);
    }
}

extern "C" void kernel_launch(void* const* d_in, const int* in_sizes, int n_in,
                              void* d_out, int out_size, void* d_ws, size_t ws_size,
                              hipStream_t stream) {
  (void)in_sizes; (void)n_in; (void)out_size; (void)ws_size;
  const float* x    = (const float*)d_in[0];
  const float* cosp = (const float*)d_in[1];
  const float* sinp = (const float*)d_in[2];
  const float* Wq   = (const float*)d_in[3];
  const float* bq   = (const float*)d_in[4];
  const float* Wk   = (const float*)d_in[5];
  const float* bk   = (const float*)d_in[6];
  const float* Wv   = (const float*)d_in[7];
  const float* bv   = (const float*)d_in[8];
  const float* Wo   = (const float*)d_in[9];
  const float* bo   = (const float*)d_in[10];
  float* out = (float*)d_out;

  char* ws = (char*)d_ws;
  _Float16* xh   = (_Float16*)(ws);                    // 33.55 MB; later reused as attn-out
  _Float16* wcat = (_Float16*)(ws + 33554432);         // 8.39 MB (Wq|Wk|Wv|Wo rows)
  _Float16* Qb   = (_Float16*)(ws + 41943040);         // 33.55 MB
  _Float16* Kb   = (_Float16*)(ws + 75497472);         // 33.55 MB
  _Float16* Vb   = (_Float16*)(ws + 109051904);        // 33.55 MB -> total 136 MB

  cast_all<<<dim3(20480), dim3(256), 0, stream>>>(x, Wq, Wk, Wv, Wo, xh, wcat);

  gemm_nt<0><<<dim3(24, 128), dim3(256), 0, stream>>>(
      xh, wcat, Qb, Kb, Vb, bq, bk, bv, cosp, sinp, (float*)nullptr, (const float*)nullptr);

  attn<<<dim3(16, 256), dim3(256), 0, stream>>>(Qb, Kb, Vb, xh);

  gemm_nt<1><<<dim3(8, 128), dim3(256), 0, stream>>>(
      xh, wcat + (long)3072 * 1024, (_Float16*)nullptr, (_Float16*)nullptr, (_Float16*)nullptr,
      (const float*)nullptr, (const float*)nullptr, (const float*)nullptr,
      (const float*)nullptr, (const float*)nullptr, out, bo);
}

// Round 5
// 501.032 us; speedup vs baseline: 1.1767x; 1.1767x over previous
//
#include <hip/hip_runtime.h>
#include <hip/hip_bf16.h>
#include <stdint.h>

#define Bb 16
#define Ss 1024
#define Dd 1024
#define NHh 16
#define HDd 64
#define Mm 16384  // Bb*Ss

typedef _Float16 half8 __attribute__((ext_vector_type(8)));
typedef float f32x4 __attribute__((ext_vector_type(4)));

__device__ __forceinline__ void gload_lds16(const _Float16* g, _Float16* l) {
  auto* gp = (const __attribute__((address_space(1))) unsigned int*)(g);
  auto* lp = (__attribute__((address_space(3))) unsigned int*)(l);
  __builtin_amdgcn_global_load_lds(gp, lp, 16, 0, 0);
}

__device__ __forceinline__ float fexp2(float x) { return __builtin_amdgcn_exp2f(x); }

// ---------------- cast fp32 -> fp16 (x and concatenated weights) ----------------
__global__ void cast_all(const float* __restrict__ x,
                         const float* __restrict__ wq, const float* __restrict__ wk,
                         const float* __restrict__ wv, const float* __restrict__ wo,
                         _Float16* __restrict__ xh, _Float16* __restrict__ wcat) {
  const long NX = (long)Mm * Dd / 4;   // 4194304 chunks of 4 floats
  const long NW = (long)Dd * Dd / 4;   // 262144 per weight matrix
  long c = (long)blockIdx.x * blockDim.x + threadIdx.x;
  const float* src;
  _Float16* dst;
  long o;
  if (c < NX) {
    src = x; o = c; dst = xh;
  } else {
    long cw = c - NX;
    int m = (int)(cw / NW);
    o = cw - (long)m * NW;
    src = (m == 0) ? wq : (m == 1) ? wk : (m == 2) ? wv : wo;
    dst = wcat + (long)m * (Dd * Dd);
  }
  float4 v = reinterpret_cast<const float4*>(src)[o];
  _Float16 h[4] = {(_Float16)v.x, (_Float16)v.y, (_Float16)v.z, (_Float16)v.w};
  reinterpret_cast<uint64_t*>(dst)[o] = *reinterpret_cast<uint64_t*>(h);
}

// ---------------- NT GEMM: C[m,n] = sum_k A[m,k]*B[n,k], 128x128x32 tiles ----------------
// EPI 0: QKV projection epilogue. Q,K: bias + RoPE + scatter to (b,h,s,d) fp16.
//        V: bias + TRANSPOSED store to (b,h,d,s) fp16 (kills the attn LDS transpose).
// EPI 1: out projection epilogue (bias + fp32 store)
template <int EPI>
__global__ __launch_bounds__(256, 2) void gemm_nt(
    const _Float16* __restrict__ A, const _Float16* __restrict__ Bm,
    _Float16* __restrict__ qo, _Float16* __restrict__ ko, _Float16* __restrict__ vo,
    const float* __restrict__ bq, const float* __restrict__ bk, const float* __restrict__ bv,
    const float* __restrict__ cosp, const float* __restrict__ sinp,
    float* __restrict__ outp, const float* __restrict__ bo) {
  __shared__ __align__(16) _Float16 As[128 * 32];
  __shared__ __align__(16) _Float16 Bs[128 * 32];
  const int t = threadIdx.x;
  const int w = t >> 6, l = t & 63;
  const int g = l >> 4, ln = l & 15;
  const int wr = w >> 1, wc = w & 1;
  const long rowbase = (long)blockIdx.y * 128;
  const long colbase = (long)blockIdx.x * 128;
  const _Float16* Arow0 = A + rowbase * Dd;
  const _Float16* Brow0 = Bm + colbase * Dd;

  f32x4 acc[4][4];
#pragma unroll
  for (int i = 0; i < 4; ++i)
#pragma unroll
    for (int j = 0; j < 4; ++j) acc[i][j] = f32x4{0.f, 0.f, 0.f, 0.f};

  for (int kt = 0; kt < 32; ++kt) {
    const int kof = kt * 32;
#pragma unroll
    for (int h = 0; h < 2; ++h) {
      int chunk = t + h * 256;          // 0..511 ; 16B per chunk
      int r = chunk >> 2;
      int cc = (chunk & 3) * 8;
      gload_lds16(Arow0 + (long)r * Dd + kof + cc, &As[chunk * 8]);
      gload_lds16(Brow0 + (long)r * Dd + kof + cc, &Bs[chunk * 8]);
    }
    __syncthreads();
    half8 af[4], bf[4];
#pragma unroll
    for (int i = 0; i < 4; ++i) {
      af[i] = *reinterpret_cast<const half8*>(&As[(wr * 64 + i * 16 + ln) * 32 + g * 8]);
      bf[i] = *reinterpret_cast<const half8*>(&Bs[(wc * 64 + i * 16 + ln) * 32 + g * 8]);
    }
#pragma unroll
    for (int i = 0; i < 4; ++i)
#pragma unroll
      for (int j = 0; j < 4; ++j)
        acc[i][j] = __builtin_amdgcn_mfma_f32_16x16x32_f16(af[i], bf[j], acc[i][j], 0, 0, 0);
    __syncthreads();
  }

  if (EPI == 0) {
#pragma unroll
    for (int j = 0; j < 4; ++j) {
      long n = colbase + wc * 64 + j * 16 + ln;
      int mat = (int)(n >> 10);          // 0=q 1=k 2=v (uniform across wave)
      int col = (int)(n & 1023);
      int hh = col >> 6, hd = col & 63;
      float bias = (mat == 0) ? bq[col] : (mat == 1) ? bk[col] : bv[col];
      if (mat < 2) {
        _Float16* dst = (mat == 0) ? qo : ko;
#pragma unroll
        for (int i = 0; i < 4; ++i) {
#pragma unroll
          for (int r = 0; r < 4; ++r) {
            long row = rowbase + wr * 64 + i * 16 + g * 4 + r;
            int b = (int)(row >> 10), s = (int)(row & 1023);
            float val = acc[i][j][r] + bias;
            float part = __shfl_xor(val, 1);
            float cv = cosp[s * HDd + hd];
            float sv = sinp[s * HDd + hd];
            val = val * cv + ((hd & 1) ? part : -part) * sv;
            dst[((long)(b * NHh + hh) * Ss + s) * HDd + hd] = (_Float16)val;
          }
        }
      } else {
        // V: transposed store (b,h,d,s); 4 consecutive s packed into one 8B store
#pragma unroll
        for (int i = 0; i < 4; ++i) {
          long row0 = rowbase + wr * 64 + i * 16 + g * 4;
          int b = (int)(row0 >> 10), s = (int)(row0 & 1023);
          _Float16 p4[4];
#pragma unroll
          for (int r = 0; r < 4; ++r) p4[r] = (_Float16)(acc[i][j][r] + bias);
          long addr = ((long)((b * NHh + hh) * HDd + hd)) * Ss + s;
          *reinterpret_cast<uint64_t*>(&vo[addr]) = *reinterpret_cast<uint64_t*>(p4);
        }
      }
    }
  } else {
#pragma unroll
    for (int j = 0; j < 4; ++j) {
      long n = colbase + wc * 64 + j * 16 + ln;
      float bias = bo[n];
#pragma unroll
      for (int i = 0; i < 4; ++i)
#pragma unroll
        for (int r = 0; r < 4; ++r) {
          long row = rowbase + wr * 64 + i * 16 + g * 4 + r;
          outp[row * Dd + n] = acc[i][j][r] + bias;
        }
    }
  }
}

// ---------------- flash attention: one block = 64 q-rows of one (b,h) pair ----------------
// K is (pair, s, d); Vt_g is (pair, d, s) -- pre-transposed by the QKV GEMM epilogue.
__global__ __launch_bounds__(256, 2) void attn(
    const _Float16* __restrict__ Q, const _Float16* __restrict__ K,
    const _Float16* __restrict__ Vt_g, _Float16* __restrict__ O) {
  __shared__ __align__(16) _Float16 Ks[64 * 72];   // [krow][d] padded
  __shared__ __align__(16) _Float16 Vt[64 * 72];   // [d][krow] padded
  __shared__ __align__(16) _Float16 Ps[4 * 16 * 72];  // per-wave [q][kcol] padded
  const int t = threadIdx.x;
  const int w = t >> 6, l = t & 63;
  const int g = l >> 4, ln = l & 15;
  const int pair = blockIdx.y;       // b*16 + h
  const int qbase = blockIdx.x * 64;
  const long pbase = (long)pair * Ss * HDd;
  const float scale2 = 0.125f * 1.44269504088896f;  // 64^-0.5 * log2(e)

  // Q fragments for this wave's 16 q-rows (held in registers for all iterations)
  half8 qf[2];
  {
    long qr = qbase + w * 16 + ln;
    const _Float16* qp = Q + pbase + qr * HDd + g * 8;
    qf[0] = *reinterpret_cast<const half8*>(qp);
    qf[1] = *reinterpret_cast<const half8*>(qp + 32);
  }

  float m_i = -1e30f, l_i = 0.0f;
  f32x4 acc_o[4];
#pragma unroll
  for (int c = 0; c < 4; ++c) acc_o[c] = f32x4{0.f, 0.f, 0.f, 0.f};

  for (int kt = 0; kt < 16; ++kt) {
    // stage K tile [64 s][64 d] and V^T tile [64 d][64 s]: pure b128 row loads
#pragma unroll
    for (int h2 = 0; h2 < 2; ++h2) {
      int chunk = t + h2 * 256;        // 0..511
      int r = chunk >> 3;              // 0..63
      int cc = (chunk & 7) * 8;        // 0..56
      const _Float16* kp = K + pbase + (long)(kt * 64 + r) * HDd + cc;
      *reinterpret_cast<half8*>(&Ks[r * 72 + cc]) = *reinterpret_cast<const half8*>(kp);
      const _Float16* vp = Vt_g + pbase + (long)r * Ss + kt * 64 + cc;
      *reinterpret_cast<half8*>(&Vt[r * 72 + cc]) = *reinterpret_cast<const half8*>(vp);
    }
    __syncthreads();

    // S^T tile: mfma(A=K rows, B=Q^T) -> D[kcol][qrow]
    f32x4 accs[4];
#pragma unroll
    for (int c = 0; c < 4; ++c) {
      half8 kf0 = *reinterpret_cast<const half8*>(&Ks[(c * 16 + ln) * 72 + g * 8]);
      half8 kf1 = *reinterpret_cast<const half8*>(&Ks[(c * 16 + ln) * 72 + 32 + g * 8]);
      f32x4 a = f32x4{0.f, 0.f, 0.f, 0.f};
      a = __builtin_amdgcn_mfma_f32_16x16x32_f16(kf0, qf[0], a, 0, 0, 0);
      a = __builtin_amdgcn_mfma_f32_16x16x32_f16(kf1, qf[1], a, 0, 0, 0);
      accs[c] = a;
    }

    // online softmax (base-2 domain) for row q = ln; k-values split across g-groups
    float pv[16];
    float pmax = -1e30f;
#pragma unroll
    for (int c = 0; c < 4; ++c)
#pragma unroll
      for (int r = 0; r < 4; ++r) {
        float sv = accs[c][r] * scale2;
        pv[c * 4 + r] = sv;
        pmax = fmaxf(pmax, sv);
      }
    pmax = fmaxf(pmax, __shfl_xor(pmax, 16));
    pmax = fmaxf(pmax, __shfl_xor(pmax, 32));
    float m_new = fmaxf(m_i, pmax);
    float alpha = fexp2(m_i - m_new);
    float tsum = 0.0f;
#pragma unroll
    for (int z = 0; z < 16; ++z) {
      float e = fexp2(pv[z] - m_new);
      pv[z] = e;
      tsum += e;
    }
    tsum += __shfl_xor(tsum, 16);
    tsum += __shfl_xor(tsum, 32);
    l_i = l_i * alpha + tsum;
    m_i = m_new;

    // rescale acc_o rows (q = 4g + r) by that row's alpha
    float alr[4];
#pragma unroll
    for (int r = 0; r < 4; ++r) alr[r] = __shfl(alpha, g * 4 + r);
#pragma unroll
    for (int c = 0; c < 4; ++c)
#pragma unroll
      for (int r = 0; r < 4; ++r) acc_o[c][r] *= alr[r];

    // write P (fp16) to per-wave LDS: row q=ln, cols c*16+4g+r
    _Float16* prow = &Ps[(w * 16 + ln) * 72];
#pragma unroll
    for (int c = 0; c < 4; ++c) {
      _Float16 p4[4] = {(_Float16)pv[c * 4 + 0], (_Float16)pv[c * 4 + 1],
                        (_Float16)pv[c * 4 + 2], (_Float16)pv[c * 4 + 3]};
      *reinterpret_cast<uint2*>(&prow[c * 16 + g * 4]) = *reinterpret_cast<uint2*>(p4);
    }

    // PV: acc_o[c'] += P(16x64) * V(64x16 per sub-tile)
#pragma unroll
    for (int kh = 0; kh < 2; ++kh) {
      half8 pf = *reinterpret_cast<const half8*>(&Ps[(w * 16 + ln) * 72 + kh * 32 + g * 8]);
#pragma unroll
      for (int c = 0; c < 4; ++c) {
        half8 vf = *reinterpret_cast<const half8*>(&Vt[(c * 16 + ln) * 72 + kh * 32 + g * 8]);
        acc_o[c] = __builtin_amdgcn_mfma_f32_16x16x32_f16(pf, vf, acc_o[c], 0, 0, 0);
      }
    }
    __syncthreads();
  }

  // epilogue: normalize rows and store to (b, s, h*64+d) fp16
  const int b = pair >> 4, hh = pair & 15;
  float linv[4];
#pragma unroll
  for (int r = 0; r < 4; ++r) linv[r] = 1.0f / __shfl(l_i, g * 4 + r);
#pragma unroll
  for (int c = 0; c < 4; ++c)
#pragma unroll
    for (int r = 0; r < 4; ++r) {
      int s = qbase + w * 16 + g * 4 + r;
      long addr = ((long)(b * Ss + s)) * Dd + hh * HDd + c * 16 + ln;
      O[addr] = (_Float16)(acc_o[c][r] * linv[r]);
    }
}

extern "C" void kernel_launch(void* const* d_in, const int* in_sizes, int n_in,
                              void* d_out, int out_size, void* d_ws, size_t ws_size,
                              hipStream_t stream) {
  (void)in_sizes; (void)n_in; (void)out_size; (void)ws_size;
  const float* x    = (const float*)d_in[0];
  const float* cosp = (const float*)d_in[1];
  const float* sinp = (const float*)d_in[2];
  const float* Wq   = (const float*)d_in[3];
  const float* bq   = (const float*)d_in[4];
  const float* Wk   = (const float*)d_in[5];
  const float* bk   = (const float*)d_in[6];
  const float* Wv   = (const float*)d_in[7];
  const float* bv   = (const float*)d_in[8];
  const float* Wo   = (const float*)d_in[9];
  const float* bo   = (const float*)d_in[10];
  float* out = (float*)d_out;

  char* ws = (char*)d_ws;
  _Float16* xh   = (_Float16*)(ws);                    // 33.55 MB; later reused as attn-out
  _Float16* wcat = (_Float16*)(ws + 33554432);         // 8.39 MB (Wq|Wk|Wv|Wo rows)
  _Float16* Qb   = (_Float16*)(ws + 41943040);         // 33.55 MB
  _Float16* Kb   = (_Float16*)(ws + 75497472);         // 33.55 MB
  _Float16* Vb   = (_Float16*)(ws + 109051904);        // 33.55 MB, V^T (b,h,d,s)

  cast_all<<<dim3(20480), dim3(256), 0, stream>>>(x, Wq, Wk, Wv, Wo, xh, wcat);

  gemm_nt<0><<<dim3(24, 128), dim3(256), 0, stream>>>(
      xh, wcat, Qb, Kb, Vb, bq, bk, bv, cosp, sinp, (float*)nullptr, (const float*)nullptr);

  attn<<<dim3(16, 256), dim3(256), 0, stream>>>(Qb, Kb, Vb, xh);

  gemm_nt<1><<<dim3(8, 128), dim3(256), 0, stream>>>(
      xh, wcat + (long)3072 * 1024, (_Float16*)nullptr, (_Float16*)nullptr, (_Float16*)nullptr,
      (const float*)nullptr, (const float*)nullptr, (const float*)nullptr,
      (const float*)nullptr, (const float*)nullptr, out, bo);
}

// Round 6
// 481.285 us; speedup vs baseline: 1.2250x; 1.0410x over previous
//
#include <hip/hip_runtime.h>
#include <hip/hip_bf16.h>
#include <stdint.h>

#define Bb 16
#define Ss 1024
#define Dd 1024
#define NHh 16
#define HDd 64
#define Mm 16384  // Bb*Ss

typedef _Float16 half8 __attribute__((ext_vector_type(8)));
typedef float f32x4 __attribute__((ext_vector_type(4)));

__device__ __forceinline__ void gload_lds16(const _Float16* g, _Float16* l) {
  auto* gp = (const __attribute__((address_space(1))) unsigned int*)(g);
  auto* lp = (__attribute__((address_space(3))) unsigned int*)(l);
  __builtin_amdgcn_global_load_lds(gp, lp, 16, 0, 0);
}

__device__ __forceinline__ float fexp2(float x) { return __builtin_amdgcn_exp2f(x); }

// ---------------- cast fp32 -> fp16 (x and concatenated weights) ----------------
__global__ void cast_all(const float* __restrict__ x,
                         const float* __restrict__ wq, const float* __restrict__ wk,
                         const float* __restrict__ wv, const float* __restrict__ wo,
                         _Float16* __restrict__ xh, _Float16* __restrict__ wcat) {
  const long NX = (long)Mm * Dd / 4;   // 4194304 chunks of 4 floats
  const long NW = (long)Dd * Dd / 4;   // 262144 per weight matrix
  long c = (long)blockIdx.x * blockDim.x + threadIdx.x;
  const float* src;
  _Float16* dst;
  long o;
  if (c < NX) {
    src = x; o = c; dst = xh;
  } else {
    long cw = c - NX;
    int m = (int)(cw / NW);
    o = cw - (long)m * NW;
    src = (m == 0) ? wq : (m == 1) ? wk : (m == 2) ? wv : wo;
    dst = wcat + (long)m * (Dd * Dd);
  }
  float4 v = reinterpret_cast<const float4*>(src)[o];
  _Float16 h[4] = {(_Float16)v.x, (_Float16)v.y, (_Float16)v.z, (_Float16)v.w};
  reinterpret_cast<uint64_t*>(dst)[o] = *reinterpret_cast<uint64_t*>(h);
}

// ---------------- NT GEMM: C[m,n] = sum_k A[m,k]*B[n,k], 128x128x32 tiles ----------------
// EPI 0: QKV projection epilogue. Q,K: bias + RoPE + scatter to (b,h,s,d) fp16.
//        V: bias + TRANSPOSED store to (b,h,d,s) fp16 (kills the attn LDS transpose).
// EPI 1: out projection epilogue (bias + fp32 store)
template <int EPI>
__global__ __launch_bounds__(256, 2) void gemm_nt(
    const _Float16* __restrict__ A, const _Float16* __restrict__ Bm,
    _Float16* __restrict__ qo, _Float16* __restrict__ ko, _Float16* __restrict__ vo,
    const float* __restrict__ bq, const float* __restrict__ bk, const float* __restrict__ bv,
    const float* __restrict__ cosp, const float* __restrict__ sinp,
    float* __restrict__ outp, const float* __restrict__ bo) {
  __shared__ __align__(16) _Float16 As[128 * 32];
  __shared__ __align__(16) _Float16 Bs[128 * 32];
  const int t = threadIdx.x;
  const int w = t >> 6, l = t & 63;
  const int g = l >> 4, ln = l & 15;
  const int wr = w >> 1, wc = w & 1;
  const long rowbase = (long)blockIdx.y * 128;
  const long colbase = (long)blockIdx.x * 128;
  const _Float16* Arow0 = A + rowbase * Dd;
  const _Float16* Brow0 = Bm + colbase * Dd;

  f32x4 acc[4][4];
#pragma unroll
  for (int i = 0; i < 4; ++i)
#pragma unroll
    for (int j = 0; j < 4; ++j) acc[i][j] = f32x4{0.f, 0.f, 0.f, 0.f};

  for (int kt = 0; kt < 32; ++kt) {
    const int kof = kt * 32;
#pragma unroll
    for (int h = 0; h < 2; ++h) {
      int chunk = t + h * 256;          // 0..511 ; 16B per chunk
      int r = chunk >> 2;
      int cc = (chunk & 3) * 8;
      gload_lds16(Arow0 + (long)r * Dd + kof + cc, &As[chunk * 8]);
      gload_lds16(Brow0 + (long)r * Dd + kof + cc, &Bs[chunk * 8]);
    }
    __syncthreads();
    half8 af[4], bf[4];
#pragma unroll
    for (int i = 0; i < 4; ++i) {
      af[i] = *reinterpret_cast<const half8*>(&As[(wr * 64 + i * 16 + ln) * 32 + g * 8]);
      bf[i] = *reinterpret_cast<const half8*>(&Bs[(wc * 64 + i * 16 + ln) * 32 + g * 8]);
    }
#pragma unroll
    for (int i = 0; i < 4; ++i)
#pragma unroll
      for (int j = 0; j < 4; ++j)
        acc[i][j] = __builtin_amdgcn_mfma_f32_16x16x32_f16(af[i], bf[j], acc[i][j], 0, 0, 0);
    __syncthreads();
  }

  if (EPI == 0) {
#pragma unroll
    for (int j = 0; j < 4; ++j) {
      long n = colbase + wc * 64 + j * 16 + ln;
      int mat = (int)(n >> 10);          // 0=q 1=k 2=v (uniform across wave)
      int col = (int)(n & 1023);
      int hh = col >> 6, hd = col & 63;
      float bias = (mat == 0) ? bq[col] : (mat == 1) ? bk[col] : bv[col];
      if (mat < 2) {
        _Float16* dst = (mat == 0) ? qo : ko;
#pragma unroll
        for (int i = 0; i < 4; ++i) {
#pragma unroll
          for (int r = 0; r < 4; ++r) {
            long row = rowbase + wr * 64 + i * 16 + g * 4 + r;
            int b = (int)(row >> 10), s = (int)(row & 1023);
            float val = acc[i][j][r] + bias;
            float part = __shfl_xor(val, 1);
            float cv = cosp[s * HDd + hd];
            float sv = sinp[s * HDd + hd];
            val = val * cv + ((hd & 1) ? part : -part) * sv;
            dst[((long)(b * NHh + hh) * Ss + s) * HDd + hd] = (_Float16)val;
          }
        }
      } else {
        // V: transposed store (b,h,d,s); 4 consecutive s packed into one 8B store
#pragma unroll
        for (int i = 0; i < 4; ++i) {
          long row0 = rowbase + wr * 64 + i * 16 + g * 4;
          int b = (int)(row0 >> 10), s = (int)(row0 & 1023);
          _Float16 p4[4];
#pragma unroll
          for (int r = 0; r < 4; ++r) p4[r] = (_Float16)(acc[i][j][r] + bias);
          long addr = ((long)((b * NHh + hh) * HDd + hd)) * Ss + s;
          *reinterpret_cast<uint64_t*>(&vo[addr]) = *reinterpret_cast<uint64_t*>(p4);
        }
      }
    }
  } else {
#pragma unroll
    for (int j = 0; j < 4; ++j) {
      long n = colbase + wc * 64 + j * 16 + ln;
      float bias = bo[n];
#pragma unroll
      for (int i = 0; i < 4; ++i)
#pragma unroll
        for (int r = 0; r < 4; ++r) {
          long row = rowbase + wr * 64 + i * 16 + g * 4 + r;
          outp[row * Dd + n] = acc[i][j][r] + bias;
        }
    }
  }
}

// ---------------- flash attention ----------------
// 1-D grid, XCD pair-affinity swizzle: all 16 q-tile blocks of a (b,h) pair land on
// the same XCD (id&7) so the pair's 256-KB K/V working set stays L2-resident.
// T14 async staging: tile kt+1's global loads issue before compute of tile kt,
// ds_write after the read-completion barrier (HBM latency hides under compute).
// K is (pair, s, d); Vt_g is (pair, d, s) -- pre-transposed by the QKV GEMM epilogue.
__global__ __launch_bounds__(256, 2) void attn(
    const _Float16* __restrict__ Q, const _Float16* __restrict__ K,
    const _Float16* __restrict__ Vt_g, _Float16* __restrict__ O) {
  __shared__ __align__(16) _Float16 Ks[64 * 72];   // [krow][d] padded
  __shared__ __align__(16) _Float16 Vt[64 * 72];   // [d][krow] padded
  __shared__ __align__(16) _Float16 Ps[4 * 16 * 72];  // per-wave [q][kcol] padded
  const int t = threadIdx.x;
  const int w = t >> 6, l = t & 63;
  const int g = l >> 4, ln = l & 15;
  // XCD-affinity decode (8 XCDs, 4096 blocks, 512/XCD = 32 pairs x 16 qtiles)
  const int id = blockIdx.x;
  const int xcd = id & 7, idx = id >> 3;
  const int pair = xcd + 8 * (idx >> 4);   // b*16 + h
  const int qbase = (idx & 15) * 64;
  const long pbase = (long)pair * Ss * HDd;
  const float scale2 = 0.125f * 1.44269504088896f;  // 64^-0.5 * log2(e)

  // staging geometry: chunk = t + h2*256; r = chunk>>3 (0..63); cc = (chunk&7)*8
  const int r0 = t >> 3, cc0 = (t & 7) * 8;          // h2 = 0
  const int r1 = (t + 256) >> 3, cc1 = cc0;          // h2 = 1 (r1 = r0+32)

  // Q fragments for this wave's 16 q-rows (held in registers for all iterations)
  half8 qf[2];
  {
    long qr = qbase + w * 16 + ln;
    const _Float16* qp = Q + pbase + qr * HDd + g * 8;
    qf[0] = *reinterpret_cast<const half8*>(qp);
    qf[1] = *reinterpret_cast<const half8*>(qp + 32);
  }

  float m_i = -1e30f, l_i = 0.0f;
  f32x4 acc_o[4];
#pragma unroll
  for (int c = 0; c < 4; ++c) acc_o[c] = f32x4{0.f, 0.f, 0.f, 0.f};

  // prologue: tile 0 -> regs -> LDS
  half8 kreg0, kreg1, vreg0, vreg1;
  kreg0 = *reinterpret_cast<const half8*>(K + pbase + (long)r0 * HDd + cc0);
  kreg1 = *reinterpret_cast<const half8*>(K + pbase + (long)r1 * HDd + cc1);
  vreg0 = *reinterpret_cast<const half8*>(Vt_g + pbase + (long)r0 * Ss + cc0);
  vreg1 = *reinterpret_cast<const half8*>(Vt_g + pbase + (long)r1 * Ss + cc1);
  *reinterpret_cast<half8*>(&Ks[r0 * 72 + cc0]) = kreg0;
  *reinterpret_cast<half8*>(&Ks[r1 * 72 + cc1]) = kreg1;
  *reinterpret_cast<half8*>(&Vt[r0 * 72 + cc0]) = vreg0;
  *reinterpret_cast<half8*>(&Vt[r1 * 72 + cc1]) = vreg1;

  for (int kt = 0; kt < 16; ++kt) {
    __syncthreads();   // tile kt visible in LDS

    // issue tile kt+1 global loads now; they complete under this tile's compute
    if (kt + 1 < 16) {
      const int kb = (kt + 1) * 64;
      kreg0 = *reinterpret_cast<const half8*>(K + pbase + (long)(kb + r0) * HDd + cc0);
      kreg1 = *reinterpret_cast<const half8*>(K + pbase + (long)(kb + r1) * HDd + cc1);
      vreg0 = *reinterpret_cast<const half8*>(Vt_g + pbase + (long)r0 * Ss + kb + cc0);
      vreg1 = *reinterpret_cast<const half8*>(Vt_g + pbase + (long)r1 * Ss + kb + cc1);
    }

    // S^T tile: mfma(A=K rows, B=Q^T) -> D[kcol][qrow]
    f32x4 accs[4];
#pragma unroll
    for (int c = 0; c < 4; ++c) {
      half8 kf0 = *reinterpret_cast<const half8*>(&Ks[(c * 16 + ln) * 72 + g * 8]);
      half8 kf1 = *reinterpret_cast<const half8*>(&Ks[(c * 16 + ln) * 72 + 32 + g * 8]);
      f32x4 a = f32x4{0.f, 0.f, 0.f, 0.f};
      a = __builtin_amdgcn_mfma_f32_16x16x32_f16(kf0, qf[0], a, 0, 0, 0);
      a = __builtin_amdgcn_mfma_f32_16x16x32_f16(kf1, qf[1], a, 0, 0, 0);
      accs[c] = a;
    }

    // online softmax (base-2 domain) for row q = ln; k-values split across g-groups
    float pv[16];
    float pmax = -1e30f;
#pragma unroll
    for (int c = 0; c < 4; ++c)
#pragma unroll
      for (int r = 0; r < 4; ++r) {
        float sv = accs[c][r] * scale2;
        pv[c * 4 + r] = sv;
        pmax = fmaxf(pmax, sv);
      }
    pmax = fmaxf(pmax, __shfl_xor(pmax, 16));
    pmax = fmaxf(pmax, __shfl_xor(pmax, 32));
    float m_new = fmaxf(m_i, pmax);
    float alpha = fexp2(m_i - m_new);
    float tsum = 0.0f;
#pragma unroll
    for (int z = 0; z < 16; ++z) {
      float e = fexp2(pv[z] - m_new);
      pv[z] = e;
      tsum += e;
    }
    tsum += __shfl_xor(tsum, 16);
    tsum += __shfl_xor(tsum, 32);
    l_i = l_i * alpha + tsum;
    m_i = m_new;

    // rescale acc_o rows (q = 4g + r) by that row's alpha
    float alr[4];
#pragma unroll
    for (int r = 0; r < 4; ++r) alr[r] = __shfl(alpha, g * 4 + r);
#pragma unroll
    for (int c = 0; c < 4; ++c)
#pragma unroll
      for (int r = 0; r < 4; ++r) acc_o[c][r] *= alr[r];

    // write P (fp16) to per-wave LDS: row q=ln, cols c*16+4g+r
    _Float16* prow = &Ps[(w * 16 + ln) * 72];
#pragma unroll
    for (int c = 0; c < 4; ++c) {
      _Float16 p4[4] = {(_Float16)pv[c * 4 + 0], (_Float16)pv[c * 4 + 1],
                        (_Float16)pv[c * 4 + 2], (_Float16)pv[c * 4 + 3]};
      *reinterpret_cast<uint2*>(&prow[c * 16 + g * 4]) = *reinterpret_cast<uint2*>(p4);
    }

    // PV: acc_o[c'] += P(16x64) * V(64x16 per sub-tile)
#pragma unroll
    for (int kh = 0; kh < 2; ++kh) {
      half8 pf = *reinterpret_cast<const half8*>(&Ps[(w * 16 + ln) * 72 + kh * 32 + g * 8]);
#pragma unroll
      for (int c = 0; c < 4; ++c) {
        half8 vf = *reinterpret_cast<const half8*>(&Vt[(c * 16 + ln) * 72 + kh * 32 + g * 8]);
        acc_o[c] = __builtin_amdgcn_mfma_f32_16x16x32_f16(pf, vf, acc_o[c], 0, 0, 0);
      }
    }
    __syncthreads();   // all LDS reads of tile kt done

    // write tile kt+1 regs -> LDS (compiler inserts vmcnt wait on reg use)
    if (kt + 1 < 16) {
      *reinterpret_cast<half8*>(&Ks[r0 * 72 + cc0]) = kreg0;
      *reinterpret_cast<half8*>(&Ks[r1 * 72 + cc1]) = kreg1;
      *reinterpret_cast<half8*>(&Vt[r0 * 72 + cc0]) = vreg0;
      *reinterpret_cast<half8*>(&Vt[r1 * 72 + cc1]) = vreg1;
    }
  }

  // epilogue: normalize rows and store to (b, s, h*64+d) fp16
  const int b = pair >> 4, hh = pair & 15;
  float linv[4];
#pragma unroll
  for (int r = 0; r < 4; ++r) linv[r] = 1.0f / __shfl(l_i, g * 4 + r);
#pragma unroll
  for (int c = 0; c < 4; ++c)
#pragma unroll
    for (int r = 0; r < 4; ++r) {
      int s = qbase + w * 16 + g * 4 + r;
      long addr = ((long)(b * Ss + s)) * Dd + hh * HDd + c * 16 + ln;
      O[addr] = (_Float16)(acc_o[c][r] * linv[r]);
    }
}

extern "C" void kernel_launch(void* const* d_in, const int* in_sizes, int n_in,
                              void* d_out, int out_size, void* d_ws, size_t ws_size,
                              hipStream_t stream) {
  (void)in_sizes; (void)n_in; (void)out_size; (void)ws_size;
  const float* x    = (const float*)d_in[0];
  const float* cosp = (const float*)d_in[1];
  const float* sinp = (const float*)d_in[2];
  const float* Wq   = (const float*)d_in[3];
  const float* bq   = (const float*)d_in[4];
  const float* Wk   = (const float*)d_in[5];
  const float* bk   = (const float*)d_in[6];
  const float* Wv   = (const float*)d_in[7];
  const float* bv   = (const float*)d_in[8];
  const float* Wo   = (const float*)d_in[9];
  const float* bo   = (const float*)d_in[10];
  float* out = (float*)d_out;

  char* ws = (char*)d_ws;
  _Float16* xh   = (_Float16*)(ws);                    // 33.55 MB; later reused as attn-out
  _Float16* wcat = (_Float16*)(ws + 33554432);         // 8.39 MB (Wq|Wk|Wv|Wo rows)
  _Float16* Qb   = (_Float16*)(ws + 41943040);         // 33.55 MB
  _Float16* Kb   = (_Float16*)(ws + 75497472);         // 33.55 MB
  _Float16* Vb   = (_Float16*)(ws + 109051904);        // 33.55 MB, V^T (b,h,d,s)

  cast_all<<<dim3(20480), dim3(256), 0, stream>>>(x, Wq, Wk, Wv, Wo, xh, wcat);

  gemm_nt<0><<<dim3(24, 128), dim3(256), 0, stream>>>(
      xh, wcat, Qb, Kb, Vb, bq, bk, bv, cosp, sinp, (float*)nullptr, (const float*)nullptr);

  attn<<<dim3(4096), dim3(256), 0, stream>>>(Qb, Kb, Vb, xh);

  gemm_nt<1><<<dim3(8, 128), dim3(256), 0, stream>>>(
      xh, wcat + (long)3072 * 1024, (_Float16*)nullptr, (_Float16*)nullptr, (_Float16*)nullptr,
      (const float*)nullptr, (const float*)nullptr, (const float*)nullptr,
      (const float*)nullptr, (const float*)nullptr, out, bo);
}